// Round 9
// baseline (368.013 us; speedup 1.0000x reference)
//
#include <hip/hip_runtime.h>
#include <hip/hip_bf16.h>

namespace {

constexpr int H      = 256;  // model dim
constexpr int C      = 259;  // k/v channel dim
constexpr int CP     = 260;  // padded LDS row pitch (1040 B, 16B-aligned)
constexpr int E      = 32;   // neighbors
constexpr int NHEAD  = 8;
constexpr int NB     = 4;    // nodes per block
constexpr float SCALE = 0.17677669529663687f; // 1/sqrt(32)

__device__ __forceinline__ float dot4(float4 a, float4 b) {
    return a.x * b.x + a.y * b.y + a.z * b.z + a.w * b.w;
}

// f32 everywhere (no unpack VALU ops — R8's bf16 packing was a net loss).
// Load-batch discipline (R8, spill-free at 64 VGPR): outer loops unroll 1,
// global-load loops unroll <=2 (<=4 vectors in flight). LDS-read loops may
// unroll deeper (R2 precedent: not batched by the allocator).
__global__ __launch_bounds__(256, 4) void mha_neigh_kernel(
    const float* __restrict__ q, const float* __restrict__ kk, const float* __restrict__ vv,
    const float* __restrict__ Wq, const float* __restrict__ Wk,
    const float* __restrict__ Wv, const float* __restrict__ Wo,
    float* __restrict__ outp, int n)
{
    // 33280 + 4096 = 37376 B. Occupancy is VGPR-capped (~16 waves/CU at 64
    // VGPR on this chip), so the larger f32 LDS costs nothing.
    __shared__ __align__(16) float w_lds[NB * NHEAD * CP]; // q-stage -> w -> vbar
    __shared__ __align__(16) float uni[NB * 256];          // qp -> simi/att -> out

    const int t    = threadIdx.x;
    const int wv   = t >> 6;
    const int lane = t & 63;
    const int dr   = lane >> 3;  // row-octet 0..7
    const int cs   = lane & 7;   // c-chunk 0..7
    const int n0   = blockIdx.x * NB;

    int node[NB];
    #pragma unroll
    for (int nb = 0; nb < NB; ++nb) {
        int nn = n0 + nb;
        node[nb] = (nn < n) ? nn : (n - 1);
    }

    // ---- P0: stage q into LDS (aliases w_lds; dead before P2 writes w)
    float* q_st = w_lds;
    #pragma unroll
    for (int nb = 0; nb < NB; ++nb) q_st[nb * 256 + t] = q[(size_t)node[nb] * H + t];
    __syncthreads();

    // ---- P1: qp[nb][row] = sum_c Wq[row][c] * q[nb][c]
    // pp unroll 1; m unroll 2 -> max 4 float4 global loads in flight.
    {
        const float4* Wq4 = (const float4*)Wq;
        #pragma unroll 1
        for (int pp = 0; pp < 4; ++pp) {
            const int row0 = (2 * pp) * 32 + wv * 8 + dr;
            const int row1 = row0 + 32;
            float acc0[NB] = {}, acc1[NB] = {};
            #pragma unroll 2
            for (int m = 0; m < 8; ++m) {
                float4 wq0 = Wq4[(size_t)row0 * 64 + cs + 8 * m];
                float4 wq1 = Wq4[(size_t)row1 * 64 + cs + 8 * m];
                #pragma unroll
                for (int nb = 0; nb < NB; ++nb) {
                    float4 qv = *(const float4*)&q_st[nb * 256 + cs * 4 + 32 * m];
                    acc0[nb] += dot4(wq0, qv);
                    acc1[nb] += dot4(wq1, qv);
                }
            }
            #pragma unroll
            for (int off = 1; off <= 4; off <<= 1) {
                #pragma unroll
                for (int nb = 0; nb < NB; ++nb) {
                    acc0[nb] += __shfl_xor(acc0[nb], off, 64);
                    acc1[nb] += __shfl_xor(acc1[nb], off, 64);
                }
            }
            float v0 = (cs == 0) ? acc0[0] : (cs == 1) ? acc0[1] : (cs == 2) ? acc0[2] : acc0[3];
            float v1 = (cs == 0) ? acc1[0] : (cs == 1) ? acc1[1] : (cs == 2) ? acc1[2] : acc1[3];
            if (cs < 4) {
                uni[cs * 256 + row0] = v0;
                uni[cs * 256 + row1] = v1;
            }
        }
    }
    __syncthreads();   // qp visible; q_st (w_lds alias) reads complete

    // ---- P2: w[nb][h][c] = sum_d qp[nb][h*32+d] * Wk[h*32+d][c]  (f32 pair stores)
    // qq unroll 1, d4 unroll 1 -> 4 float2 weight loads in flight max.
    {
        const int h  = t >> 5;
        const int c0 = t & 31;
        #pragma unroll 1
        for (int qq = 0; qq < 4; ++qq) {
            float accE[NB] = {}, accO[NB] = {};
            #pragma unroll 1
            for (int d4 = 0; d4 < 8; ++d4) {
                float4 qp4[NB];
                #pragma unroll
                for (int nb = 0; nb < NB; ++nb)
                    qp4[nb] = *(const float4*)&uni[nb * 256 + h * 32 + d4 * 4];
                #pragma unroll
                for (int dd = 0; dd < 4; ++dd) {
                    const float* wkrow = Wk + (size_t)(h * 32 + d4 * 4 + dd) * C;
                    float2 wk2 = *(const float2*)&wkrow[2 * c0 + 64 * qq];
                    float q0 = (dd == 0) ? qp4[0].x : (dd == 1) ? qp4[0].y : (dd == 2) ? qp4[0].z : qp4[0].w;
                    float q1 = (dd == 0) ? qp4[1].x : (dd == 1) ? qp4[1].y : (dd == 2) ? qp4[1].z : qp4[1].w;
                    float q2 = (dd == 0) ? qp4[2].x : (dd == 1) ? qp4[2].y : (dd == 2) ? qp4[2].z : qp4[2].w;
                    float q3 = (dd == 0) ? qp4[3].x : (dd == 1) ? qp4[3].y : (dd == 2) ? qp4[3].z : qp4[3].w;
                    accE[0] += wk2.x * q0; accO[0] += wk2.y * q0;
                    accE[1] += wk2.x * q1; accO[1] += wk2.y * q1;
                    accE[2] += wk2.x * q2; accO[2] += wk2.y * q2;
                    accE[3] += wk2.x * q3; accO[3] += wk2.y * q3;
                }
            }
            #pragma unroll
            for (int nb = 0; nb < NB; ++nb) {
                w_lds[(nb * NHEAD + h) * CP + 2 * c0 + 64 * qq]     = accE[nb];
                w_lds[(nb * NHEAD + h) * CP + 2 * c0 + 64 * qq + 1] = accO[nb];
            }
        }
        if (c0 < 2) { // tail: c = (256,257) for c0=0, (258, 259->pad) for c0=1
            float accE[NB] = {}, accO[NB] = {};
            #pragma unroll 2
            for (int d = 0; d < 32; ++d) {
                const float* wkrow = Wk + (size_t)(h * 32 + d) * C;
                float e0 = wkrow[256 + 2 * c0];
                float e1 = (c0 == 0) ? wkrow[257] : 0.0f;
                #pragma unroll
                for (int nb = 0; nb < NB; ++nb) {
                    float qpv = uni[nb * 256 + h * 32 + d];
                    accE[nb] += e0 * qpv;
                    accO[nb] += e1 * qpv;
                }
            }
            #pragma unroll
            for (int nb = 0; nb < NB; ++nb) {
                w_lds[(nb * NHEAD + h) * CP + 256 + 2 * c0]     = accE[nb];
                w_lds[(nb * NHEAD + h) * CP + 256 + 2 * c0 + 1] = accO[nb]; // 259 = pad
            }
        }
    }
    __syncthreads();

    // ---- P3a: simi direct from global k; thread -> (e = t>>3, j = t&7)
    // nb unroll 1; m unroll 4 -> 4 float4 k-loads in flight; h full (LDS reads).
    {
        const int e = t >> 3;
        const int j = t & 7;
        #pragma unroll 1
        for (int nb = 0; nb < NB; ++nb) {
            const float* krow = kk + (size_t)node[nb] * (E * C) + (size_t)e * C;
            float acc[NHEAD] = {};
            #pragma unroll 4
            for (int m = 0; m < 8; ++m) {
                float4 k4 = *(const float4*)&krow[j * 4 + 32 * m];
                #pragma unroll
                for (int h = 0; h < NHEAD; ++h) {
                    float4 w4 = *(const float4*)&w_lds[(nb * NHEAD + h) * CP + j * 4 + 32 * m];
                    acc[h] += dot4(k4, w4);
                }
            }
            if (j == 0) { // tail c = 256..258
                float k0 = krow[256], k1 = krow[257], k2 = krow[258];
                #pragma unroll
                for (int h = 0; h < NHEAD; ++h) {
                    const float* wr = &w_lds[(nb * NHEAD + h) * CP];
                    acc[h] += k0 * wr[256] + k1 * wr[257] + k2 * wr[258];
                }
            }
            #pragma unroll
            for (int h = 0; h < NHEAD; ++h) {
                float s = acc[h];
                s += __shfl_xor(s, 1, 64);
                s += __shfl_xor(s, 2, 64);
                s += __shfl_xor(s, 4, 64);
                acc[h] = s;
            }
            float myv = 0.0f;
            #pragma unroll
            for (int h = 0; h < NHEAD; ++h) myv = (j == h) ? acc[h] : myv;
            uni[nb * 256 + e * 8 + j] = myv * SCALE;   // simi slot [nb][e][h=j]
        }
    }
    __syncthreads();

    // ---- P3b: softmax over e per head, in place (f32 att)
    {
        const int h   = t >> 5;
        const int e32 = t & 31;
        #pragma unroll 1
        for (int nb = 0; nb < NB; ++nb) {
            float s = uni[nb * 256 + e32 * 8 + h];
            float mx = s;
            #pragma unroll
            for (int off = 16; off >= 1; off >>= 1) mx = fmaxf(mx, __shfl_xor(mx, off, 64));
            float p = __expf(s - mx);
            float sum = p;
            #pragma unroll
            for (int off = 16; off >= 1; off >>= 1) sum += __shfl_xor(sum, off, 64);
            uni[nb * 256 + e32 * 8 + h] = p / sum;
        }
    }
    __syncthreads();

    // ---- P3c: vbar[nb][h][c] = sum_e att[e][h] * v[e][c]; thread owns c = t
    // e unroll 4 -> 4 scalar v-loads in flight; att reads are LDS broadcasts.
    {
        #pragma unroll 1
        for (int nb = 0; nb < NB; ++nb) {
            const float* vrow = vv + (size_t)node[nb] * (E * C);
            float acc[NHEAD] = {};
            #pragma unroll 4
            for (int e = 0; e < E; ++e) {
                float4 a0 = *(const float4*)&uni[nb * 256 + e * 8];
                float4 a1 = *(const float4*)&uni[nb * 256 + e * 8 + 4];
                float x = vrow[e * C + t];
                acc[0] += a0.x * x; acc[1] += a0.y * x; acc[2] += a0.z * x; acc[3] += a0.w * x;
                acc[4] += a1.x * x; acc[5] += a1.y * x; acc[6] += a1.z * x; acc[7] += a1.w * x;
            }
            #pragma unroll
            for (int h = 0; h < NHEAD; ++h) w_lds[(nb * NHEAD + h) * CP + t] = acc[h];
            if (t < 3) { // tail c = 256..258, only wave 0 pays
                float a2[NHEAD] = {};
                #pragma unroll 2
                for (int e = 0; e < E; ++e) {
                    float4 a0 = *(const float4*)&uni[nb * 256 + e * 8];
                    float4 a1 = *(const float4*)&uni[nb * 256 + e * 8 + 4];
                    float x2 = vrow[e * C + 256 + t];
                    a2[0] += a0.x * x2; a2[1] += a0.y * x2; a2[2] += a0.z * x2; a2[3] += a0.w * x2;
                    a2[4] += a1.x * x2; a2[5] += a1.y * x2; a2[6] += a1.z * x2; a2[7] += a1.w * x2;
                }
                #pragma unroll
                for (int h = 0; h < NHEAD; ++h) w_lds[(nb * NHEAD + h) * CP + 256 + t] = a2[h];
            }
        }
    }
    __syncthreads();

    // ---- P4: out[nb][row] = sum_c vbar[nb][h][c] * Wv[row][c]; h = p per pass
    // p unroll 1; m2 unroll 2 -> 4 float4 weight loads in flight.
    #pragma unroll 1
    for (int p = 0; p < 8; ++p) {
        const int row = p * 32 + wv * 8 + dr;
        const float* wvrow = Wv + (size_t)row * C;
        float a[NB] = {};
        #pragma unroll 2
        for (int m2 = 0; m2 < 4; ++m2) {
            float4 wa = *(const float4*)&wvrow[cs * 8 + 64 * m2];     // 4B-aligned ok
            float4 wb = *(const float4*)&wvrow[cs * 8 + 64 * m2 + 4];
            #pragma unroll
            for (int nb = 0; nb < NB; ++nb) {
                float4 va = *(const float4*)&w_lds[(nb * NHEAD + p) * CP + cs * 8 + 64 * m2];
                float4 vb = *(const float4*)&w_lds[(nb * NHEAD + p) * CP + cs * 8 + 64 * m2 + 4];
                a[nb] += dot4(wa, va) + dot4(wb, vb);
            }
        }
        if (cs == 0) { // tail c = 256..258
            float w0 = wvrow[256], w1 = wvrow[257], w2 = wvrow[258];
            #pragma unroll
            for (int nb = 0; nb < NB; ++nb) {
                const float* vr = &w_lds[(nb * NHEAD + p) * CP];
                a[nb] += w0 * vr[256] + w1 * vr[257] + w2 * vr[258];
            }
        }
        #pragma unroll
        for (int off = 1; off <= 4; off <<= 1) {
            a[0] += __shfl_xor(a[0], off, 64);
            a[1] += __shfl_xor(a[1], off, 64);
            a[2] += __shfl_xor(a[2], off, 64);
            a[3] += __shfl_xor(a[3], off, 64);
        }
        float val = (cs == 0) ? a[0] : (cs == 1) ? a[1] : (cs == 2) ? a[2] : a[3];
        if (cs < 4) uni[cs * 256 + row] = val;  // out slot (att dead)
    }
    __syncthreads();

    // ---- P5: final[nb][row] = sum_dd Wo[row][dd] * out[nb][dd]; pp unroll 1, m unroll 2
    {
        const float4* Wo4 = (const float4*)Wo;
        #pragma unroll 1
        for (int pp = 0; pp < 4; ++pp) {
            const int row0 = (2 * pp) * 32 + wv * 8 + dr;
            const int row1 = row0 + 32;
            float acc0[NB] = {}, acc1[NB] = {};
            #pragma unroll 2
            for (int m = 0; m < 8; ++m) {
                float4 wo0 = Wo4[(size_t)row0 * 64 + cs + 8 * m];
                float4 wo1 = Wo4[(size_t)row1 * 64 + cs + 8 * m];
                #pragma unroll
                for (int nb = 0; nb < NB; ++nb) {
                    float4 ov = *(const float4*)&uni[nb * 256 + cs * 4 + 32 * m];
                    acc0[nb] += dot4(wo0, ov);
                    acc1[nb] += dot4(wo1, ov);
                }
            }
            #pragma unroll
            for (int off = 1; off <= 4; off <<= 1) {
                #pragma unroll
                for (int nb = 0; nb < NB; ++nb) {
                    acc0[nb] += __shfl_xor(acc0[nb], off, 64);
                    acc1[nb] += __shfl_xor(acc1[nb], off, 64);
                }
            }
            float v0 = (cs == 0) ? acc0[0] : (cs == 1) ? acc0[1] : (cs == 2) ? acc0[2] : acc0[3];
            float v1 = (cs == 0) ? acc1[0] : (cs == 1) ? acc1[1] : (cs == 2) ? acc1[2] : acc1[3];
            if (cs < 4 && (n0 + cs) < n) {
                outp[(size_t)(n0 + cs) * H + row0] = v0;
                outp[(size_t)(n0 + cs) * H + row1] = v1;
            }
        }
    }
}

} // anonymous namespace

extern "C" void kernel_launch(void* const* d_in, const int* in_sizes, int n_in,
                              void* d_out, int out_size, void* d_ws, size_t ws_size,
                              hipStream_t stream) {
    const float* q  = (const float*)d_in[0];
    const float* k  = (const float*)d_in[1];
    const float* v  = (const float*)d_in[2];
    const float* Wq = (const float*)d_in[3];
    const float* Wk = (const float*)d_in[4];
    const float* Wv = (const float*)d_in[5];
    const float* Wo = (const float*)d_in[6];
    float* out = (float*)d_out;

    const int n = in_sizes[0] / H;            // 10000 nodes
    const int blocks = (n + NB - 1) / NB;     // 2500

    mha_neigh_kernel<<<dim3(blocks), dim3(256), 0, stream>>>(
        q, k, v, Wq, Wk, Wv, Wo, out, n);
}